// Round 1
// 4311.820 us; speedup vs baseline: 1.0192x; 1.0192x over previous
//
#include <hip/hip_runtime.h>

// ---------------- model dims ----------------
#define VV 50304
#define EE 512
#define PP 320
#define NL 6
#define NH 8
#define II 1024
#define BB 2
#define SS 1024
#define HDD 40   // head dim
// 3*P = 960 qkv width

typedef __attribute__((ext_vector_type(8))) __bf16 bf16x8;
typedef __attribute__((ext_vector_type(4))) float f32x4;

__device__ __forceinline__ float gelu_tanh(float x) {
    float x3 = x * x * x;
    return 0.5f * x * (1.f + tanhf(0.7978845608028654f * (x + 0.044715f * x3)));
}

// DPP cross-lane add within a 16-lane row. Order matters: xor1, xor2 first make
// quads uniform, then ROW_HALF_MIRROR (i^7) acts as xor4 and ROW_MIRROR (i^15) as xor8.
template<int CTRL>
__device__ __forceinline__ float dpp_reduce_add(float v) {
    int s = __builtin_amdgcn_update_dpp(0, __builtin_bit_cast(int, v), CTRL, 0xF, 0xF, true);
    return v + __builtin_bit_cast(float, s);
}
#define DPPRED16(x) do { \
    x = dpp_reduce_add<0xB1>(x);  /* quad_perm [1,0,3,2] : xor 1 */ \
    x = dpp_reduce_add<0x4E>(x);  /* quad_perm [2,3,0,1] : xor 2 */ \
    x = dpp_reduce_add<0x141>(x); /* row_half_mirror     : xor 4 */ \
    x = dpp_reduce_add<0x140>(x); /* row_mirror          : xor 8 */ \
} while (0)

// ---------------- embedding gather + LN (N=512) ----------------
__global__ __launch_bounds__(64) void embed_ln_kernel(
    const int* __restrict__ ids, const float* __restrict__ embed,
    const float* __restrict__ w, const float* __restrict__ b, float* __restrict__ out)
{
    int r = blockIdx.x;
    int lane = threadIdx.x;
    long id = ids[r];
    const float* xr = embed + id * (long)EE;
    float vals[8];
    float s = 0.f;
#pragma unroll
    for (int i = 0; i < 8; ++i) { vals[i] = xr[lane + i * 64]; s += vals[i]; }
#pragma unroll
    for (int m = 32; m >= 1; m >>= 1) s += __shfl_xor(s, m);
    float mean = s * (1.f / 512.f);
    float v = 0.f;
#pragma unroll
    for (int i = 0; i < 8; ++i) { float d = vals[i] - mean; v += d * d; }
#pragma unroll
    for (int m = 32; m >= 1; m >>= 1) v += __shfl_xor(v, m);
    float rstd = rsqrtf(v * (1.f / 512.f) + 1e-5f);
    float* orow = out + (long)r * EE;
#pragma unroll
    for (int i = 0; i < 8; ++i) {
        int c = lane + i * 64;
        orow[c] = (vals[i] - mean) * rstd * w[c] + b[c];
    }
}

// ---------------- generic row LayerNorm ----------------
__global__ __launch_bounds__(64) void ln_kernel(
    const float* __restrict__ x, const float* __restrict__ w,
    const float* __restrict__ b, float* __restrict__ out, int N)
{
    int r = blockIdx.x, lane = threadIdx.x;
    const float* xr = x + (long)r * N;
    float s = 0.f;
    for (int i = lane; i < N; i += 64) s += xr[i];
#pragma unroll
    for (int m = 32; m >= 1; m >>= 1) s += __shfl_xor(s, m);
    float mean = s / (float)N;
    float v = 0.f;
    for (int i = lane; i < N; i += 64) { float d = xr[i] - mean; v += d * d; }
#pragma unroll
    for (int m = 32; m >= 1; m >>= 1) v += __shfl_xor(v, m);
    float rstd = rsqrtf(v / (float)N + 1e-5f);
    float* orow = out + (long)r * N;
    for (int i = lane; i < N; i += 64) orow[i] = (xr[i] - mean) * rstd * w[i] + b[i];
}

// ---------------- bf16 MFMA GEMM: C[M,N] = A[M,K] @ B + bias, opt gelu, opt adds
// BT=0: B is (K,N) row-major.  BT=1: B is (N,K) row-major (i.e. compute A @ B^T).
// Tile 64x64, BK=32, 4 waves (each 32x32 = 2x2 MFMA tiles of 16x16x32).
__global__ __launch_bounds__(256) void gemm_kernel(
    const float* __restrict__ A, const float* __restrict__ B,
    const float* __restrict__ bias, float* __restrict__ C,
    int M, int N, int K, int BT, int act,
    const float* __restrict__ add1, const float* __restrict__ add2)
{
    __shared__ __align__(16) __bf16 As[64 * 40];
    __shared__ __align__(16) __bf16 Bs[64 * 40];
    int tid  = threadIdx.x;
    int lane = tid & 63;
    int wv   = tid >> 6;            // 0..3
    int l15  = lane & 15, quad = lane >> 4;
    int bm = blockIdx.y * 64, bn = blockIdx.x * 64;
    int wm = (wv >> 1) * 32, wn = (wv & 1) * 32;
    f32x4 acc[2][2] = {};

    int sm = tid >> 2;              // 0..63
    int sk = (tid & 3) * 8;         // 0,8,16,24
    int bk_n = tid & 63;            // B-normal: local n
    int bk_k = (tid >> 6) * 8;      // B-normal: local k base

    for (int k0 = 0; k0 < K; k0 += 32) {
        // stage A (row-major M x K)
        {
            const float* ap = A + (long)(bm + sm) * K + k0 + sk;
            float4 a0 = *(const float4*)ap;
            float4 a1 = *(const float4*)(ap + 4);
            bf16x8 av;
            av[0] = (__bf16)a0.x; av[1] = (__bf16)a0.y; av[2] = (__bf16)a0.z; av[3] = (__bf16)a0.w;
            av[4] = (__bf16)a1.x; av[5] = (__bf16)a1.y; av[6] = (__bf16)a1.z; av[7] = (__bf16)a1.w;
            *(bf16x8*)&As[sm * 40 + sk] = av;
        }
        // stage B into Bs[n][k]
        if (BT == 0) {
            const float* bp = B + (long)(k0 + bk_k) * N + bn + bk_n;
            bf16x8 bv;
#pragma unroll
            for (int i = 0; i < 8; ++i) bv[i] = (__bf16)bp[(long)i * N];
            *(bf16x8*)&Bs[bk_n * 40 + bk_k] = bv;
        } else {
            const float* bp = B + (long)(bn + sm) * K + k0 + sk;
            float4 b0 = *(const float4*)bp;
            float4 b1 = *(const float4*)(bp + 4);
            bf16x8 bv;
            bv[0] = (__bf16)b0.x; bv[1] = (__bf16)b0.y; bv[2] = (__bf16)b0.z; bv[3] = (__bf16)b0.w;
            bv[4] = (__bf16)b1.x; bv[5] = (__bf16)b1.y; bv[6] = (__bf16)b1.z; bv[7] = (__bf16)b1.w;
            *(bf16x8*)&Bs[sm * 40 + sk] = bv;
        }
        __syncthreads();
#pragma unroll
        for (int mt = 0; mt < 2; ++mt) {
            bf16x8 af = *(const bf16x8*)&As[(wm + mt * 16 + l15) * 40 + quad * 8];
#pragma unroll
            for (int nt = 0; nt < 2; ++nt) {
                bf16x8 bfr = *(const bf16x8*)&Bs[(wn + nt * 16 + l15) * 40 + quad * 8];
                acc[mt][nt] = __builtin_amdgcn_mfma_f32_16x16x32_bf16(af, bfr, acc[mt][nt], 0, 0, 0);
            }
        }
        __syncthreads();
    }
    // epilogue: C layout col=lane&15, row=quad*4+reg
#pragma unroll
    for (int mt = 0; mt < 2; ++mt)
#pragma unroll
    for (int nt = 0; nt < 2; ++nt)
#pragma unroll
    for (int r = 0; r < 4; ++r) {
        int grow = bm + wm + mt * 16 + quad * 4 + r;
        int gcol = bn + wn + nt * 16 + l15;
        float v = acc[mt][nt][r];
        if (bias) v += bias[gcol];
        if (act == 1) v = gelu_tanh(v);
        long idx = (long)grow * N + gcol;
        if (add1) v += add1[idx];
        if (add2) v += add2[idx];
        C[idx] = v;
    }
}

// ---------------- persistent MFMA scan (dproj recurrence) ----------------
// h_t = tanh(LN(h_{t-1} @ Wtop + c_t))   ; c_t = te_t @ Wbot + dproj_b (precomputed)
// 1 block, 256 threads = 4 waves (1 per SIMD). Wave w owns output cols [80w, 80w+80)
// as five 16-wide MFMA N-tiles; its B-fragments (Wtop, bf16) live in registers/AGPRs.
// Per step: 2 barriers. LN partial sums computed from accumulators via DPP (VALU),
// c added in-wave (double-buffered prefetch, 1 step ahead).
__global__ __launch_bounds__(256, 1) void scan_kernel(
    const float* __restrict__ Wtop,   // dproj_w rows 0..319 (K x N row-major, ld=320)
    const float* __restrict__ c,      // (B,S,P) precomputed emb part incl. bias
    const float* __restrict__ lnw, const float* __restrict__ lnb,
    float* __restrict__ x)            // (B,S,P) output
{
    __shared__ __align__(16) __bf16 hA[16 * 328];   // A operand: 16 rows (2 real) x 320, pad 328
    __shared__ __align__(16) float yb2[PP * 2];     // y (incl. c), layout [col][batch]
    __shared__ __align__(16) float red[16];         // [wave][s1b0,s2b0,s1b1,s2b1]

    int tid = threadIdx.x;
    int lane = tid & 63;
    int w = tid >> 6;                 // wave 0..3
    int l15 = lane & 15, quad = lane >> 4;

    for (int i = tid; i < 16 * 328; i += 256) hA[i] = (__bf16)0.f;

    // preload Wtop fragments: B[k][n], lane holds n = 80w + 16*nt + l15, k = kt*32+quad*8+j
    bf16x8 bw[5][10];
#pragma unroll
    for (int nt = 0; nt < 5; ++nt) {
        int nn = w * 80 + nt * 16 + l15;
#pragma unroll
        for (int kt = 0; kt < 10; ++kt) {
#pragma unroll
            for (int j = 0; j < 8; ++j) {
                int kk = kt * 32 + quad * 8 + j;
                bw[nt][kt][j] = (__bf16)Wtop[(long)kk * PP + nn];
            }
        }
    }

    // finalize mapping: 640 (batch,col) values over 256 threads; v = tid, tid+256, tid+512
    int nv = (tid < 128) ? 3 : 2;
    int vb[3], vcol[3];
    vb[0] = 0;            vcol[0] = tid;
    vb[1] = (tid >= 64);  vcol[1] = vb[1] ? (tid - 64) : (tid + 256);
    vb[2] = 1;            vcol[2] = tid + 192;
    float lwv[3], lbv[3];
    long xbase[3]; int ybo[3], hao[3];
#pragma unroll
    for (int i = 0; i < 3; ++i) {
        if (i < nv) {
            lwv[i] = lnw[vcol[i]]; lbv[i] = lnb[vcol[i]];
            xbase[i] = (long)vb[i] * SS * PP + vcol[i];
            ybo[i] = vcol[i] * 2 + vb[i];
            hao[i] = vb[i] * 328 + vcol[i];
        }
    }

    // c prefetch (per-wave; address depends only on l15/nt -> broadcast across quads)
    int ccol = w * 80 + l15;
    const float* cp0 = c + ccol;                       // batch 0
    const float* cp1 = c + (long)SS * PP + ccol;       // batch 1
    float cc0[5], cc1[5];
#pragma unroll
    for (int nt = 0; nt < 5; ++nt) { cc0[nt] = cp0[nt * 16]; cc1[nt] = cp1[nt * 16]; }
    __syncthreads();

    for (int t = 0; t < SS; ++t) {
        // issue next step's c loads early (consumed next iteration)
        int tn = (t + 1 < SS) ? (t + 1) : t;
        float nc0[5], nc1[5];
#pragma unroll
        for (int nt = 0; nt < 5; ++nt) {
            nc0[nt] = cp0[(long)tn * PP + nt * 16];
            nc1[nt] = cp1[(long)tn * PP + nt * 16];
        }

        // y = h @ Wtop : 5 independent accumulator chains, shared A-fragment per kt
        f32x4 acc[5] = {};
#pragma unroll
        for (int kt = 0; kt < 10; ++kt) {
            bf16x8 a = *(const bf16x8*)&hA[l15 * 328 + kt * 32 + quad * 8];
#pragma unroll
            for (int nt = 0; nt < 5; ++nt)
                acc[nt] = __builtin_amdgcn_mfma_f32_16x16x32_bf16(a, bw[nt][kt], acc[nt], 0, 0, 0);
        }

        // add c, form LN partial sums from acc regs (real data only in quad 0;
        // DPP reduces within each 16-lane row, so other quads' garbage stays put)
        float ya[5], yc[5];
#pragma unroll
        for (int nt = 0; nt < 5; ++nt) { ya[nt] = acc[nt][0] + cc0[nt]; yc[nt] = acc[nt][1] + cc1[nt]; }
        float s10 = ya[0] + ya[1] + ya[2] + ya[3] + ya[4];
        float s20 = ya[0]*ya[0] + ya[1]*ya[1] + ya[2]*ya[2] + ya[3]*ya[3] + ya[4]*ya[4];
        float s11 = yc[0] + yc[1] + yc[2] + yc[3] + yc[4];
        float s21 = yc[0]*yc[0] + yc[1]*yc[1] + yc[2]*yc[2] + yc[3]*yc[3] + yc[4]*yc[4];
        DPPRED16(s10); DPPRED16(s20); DPPRED16(s11); DPPRED16(s21);
        if (quad == 0) {
#pragma unroll
            for (int nt = 0; nt < 5; ++nt) {
                float2 p; p.x = ya[nt]; p.y = yc[nt];
                *(float2*)&yb2[(w * 80 + nt * 16 + l15) * 2] = p;
            }
        }
        if (lane == 0) {
            f32x4 r; r[0] = s10; r[1] = s20; r[2] = s11; r[3] = s21;
            *(f32x4*)&red[w * 4] = r;
        }
        __syncthreads();

        f32x4 r0 = *(const f32x4*)&red[0];
        f32x4 r1 = *(const f32x4*)&red[4];
        f32x4 r2 = *(const f32x4*)&red[8];
        f32x4 r3 = *(const f32x4*)&red[12];
        float S10 = r0[0] + r1[0] + r2[0] + r3[0];
        float S20 = r0[1] + r1[1] + r2[1] + r3[1];
        float S11 = r0[2] + r1[2] + r2[2] + r3[2];
        float S21 = r0[3] + r1[3] + r2[3] + r3[3];
        float mean0 = S10 * (1.f / 320.f), mean1 = S11 * (1.f / 320.f);
        float rstd0 = rsqrtf(S20 * (1.f / 320.f) - mean0 * mean0 + 1e-5f);
        float rstd1 = rsqrtf(S21 * (1.f / 320.f) - mean1 * mean1 + 1e-5f);

#pragma unroll
        for (int i = 0; i < 3; ++i) {
            if (i < nv) {
                float y = yb2[ybo[i]];
                float m  = vb[i] ? mean1 : mean0;
                float rs = vb[i] ? rstd1 : rstd0;
                float z = (y - m) * rs * lwv[i] + lbv[i];
                z = fminf(fmaxf(z, -15.f), 15.f);
                float e = __expf(2.f * z);
                float h = (e - 1.f) / (e + 1.f);   // tanh(z)
                x[xbase[i] + (long)t * PP] = h;
                hA[hao[i]] = (__bf16)h;
            }
        }
#pragma unroll
        for (int nt = 0; nt < 5; ++nt) { cc0[nt] = nc0[nt]; cc1[nt] = nc1[nt]; }
        __syncthreads();
    }
}

// ---------------- RoPE in place on qkv (rot dims 0..9 of q and k per head) ----------------
__global__ __launch_bounds__(256) void rope_kernel(float* __restrict__ qkv)
{
    int t = blockIdx.x * 256 + threadIdx.x;     // 0 .. B*S*H-1
    if (t >= BB * SS * NH) return;
    int h = t & 7;
    int s = (t >> 3) & (SS - 1);
    int b = t >> 13;
    float* p = qkv + ((long)(b * SS + s)) * 960 + h * 120;
    const float inv[5] = {1.f, 0.158489319f, 0.0251188643f, 0.00398107171f, 0.000630957344f};
    float* q = p;
    float* k = p + HDD;
#pragma unroll
    for (int i = 0; i < 5; ++i) {
        float ang = (float)s * inv[i];
        float sn, cs;
        sincosf(ang, &sn, &cs);
        float q1 = q[i], q2 = q[i + 5];
        q[i]     = q1 * cs - q2 * sn;
        q[i + 5] = q2 * cs + q1 * sn;
        float k1 = k[i], k2 = k[i + 5];
        k[i]     = k1 * cs - k2 * sn;
        k[i + 5] = k2 * cs + k1 * sn;
    }
}

// ---------------- flash-style causal attention, fp32, HD=40 ----------------
// grid: qt + 16*(h + 8*b); block 256. Q-tile 64 rows.
__global__ __launch_bounds__(256) void attn_kernel(
    const float* __restrict__ qkv, float* __restrict__ ctx)
{
    int qt = blockIdx.x & 15;
    int h  = (blockIdx.x >> 4) & 7;
    int b  = blockIdx.x >> 7;
    int tid = threadIdx.x;
    __shared__ float Qs[64][41], Ks[64][41], Vs[64][41];
    __shared__ float Ss[64][65];
    __shared__ float mS[64], lS[64], aS[64];
    const float scale = 0.15811388300841897f;   // 1/sqrt(40)
    long base = (long)b * SS * 960 + h * 120;
    int q0 = qt * 64;

    for (int i = tid; i < 64 * HDD; i += 256) {
        int r = i / HDD, d = i % HDD;
        Qs[r][d] = qkv[base + (long)(q0 + r) * 960 + d] * scale;
    }
    if (tid < 64) { mS[tid] = -1e30f; lS[tid] = 0.f; }
    float O[10];
#pragma unroll
    for (int i = 0; i < 10; ++i) O[i] = 0.f;
    int qo = tid >> 2, dg = (tid & 3) * 10;     // O-phase mapping
    int sq = tid >> 2, sk16 = (tid & 3) * 16;   // S-phase mapping
    __syncthreads();

    for (int kt = 0; kt <= qt; ++kt) {
        int k0 = kt * 64;
        for (int i = tid; i < 64 * HDD; i += 256) {
            int r = i / HDD, d = i % HDD;
            Ks[r][d] = qkv[base + (long)(k0 + r) * 960 + HDD + d];
            Vs[r][d] = qkv[base + (long)(k0 + r) * 960 + 2 * HDD + d];
        }
        __syncthreads();
        // scores: each thread: 16 k's for one q row
#pragma unroll 1
        for (int kk = 0; kk < 16; ++kk) {
            int kcol = sk16 + kk;
            float s = 0.f;
#pragma unroll
            for (int d = 0; d < HDD; ++d) s += Qs[sq][d] * Ks[kcol][d];
            if (k0 + kcol > q0 + sq) s = -1e9f;
            Ss[sq][kcol] = s;
        }
        __syncthreads();
        if (tid < 64) {
            float mOld = mS[tid];
            float mNew = mOld;
            for (int j = 0; j < 64; ++j) mNew = fmaxf(mNew, Ss[tid][j]);
            float alpha = __expf(mOld - mNew);
            float psum = 0.f;
            for (int j = 0; j < 64; ++j) {
                float p = __expf(Ss[tid][j] - mNew);
                Ss[tid][j] = p;
                psum += p;
            }
            lS[tid] = lS[tid] * alpha + psum;
            mS[tid] = mNew;
            aS[tid] = alpha;
        }
        __syncthreads();
        float alpha = aS[qo];
#pragma unroll
        for (int i = 0; i < 10; ++i) O[i] *= alpha;
        for (int k = 0; k < 64; ++k) {
            float p = Ss[qo][k];
#pragma unroll
            for (int i = 0; i < 10; ++i) O[i] += p * Vs[k][dg + i];
        }
        __syncthreads();
    }
    float linv = 1.f / lS[qo];
#pragma unroll
    for (int i = 0; i < 10; ++i)
        ctx[((long)(b * SS + q0 + qo)) * PP + h * HDD + dg + i] = O[i] * linv;
}

// ---------------- launcher ----------------
extern "C" void kernel_launch(void* const* d_in, const int* in_sizes, int n_in,
                              void* d_out, int out_size, void* d_ws, size_t ws_size,
                              hipStream_t stream)
{
    (void)in_sizes; (void)n_in; (void)out_size; (void)ws_size;
    const int*   ids       = (const int*)d_in[0];
    const float* embed_w   = (const float*)d_in[1];
    const float* embed_nw  = (const float*)d_in[2];
    const float* embed_nb  = (const float*)d_in[3];
    const float* dproj_w   = (const float*)d_in[4];
    const float* dproj_b   = (const float*)d_in[5];
    const float* dproj_lnw = (const float*)d_in[6];
    const float* dproj_lnb = (const float*)d_in[7];
    const float* ln1_w     = (const float*)d_in[8];
    const float* ln1_b     = (const float*)d_in[9];
    const float* ln2_w     = (const float*)d_in[10];
    const float* ln2_b     = (const float*)d_in[11];
    const float* qkv_w     = (const float*)d_in[12];
    const float* qkv_b     = (const float*)d_in[13];
    const float* dense_w   = (const float*)d_in[14];
    const float* dense_b   = (const float*)d_in[15];
    const float* fc1_w     = (const float*)d_in[16];
    const float* fc1_b     = (const float*)d_in[17];
    const float* fc2_w     = (const float*)d_in[18];
    const float* fc2_b     = (const float*)d_in[19];
    const float* fln_w     = (const float*)d_in[20];
    const float* fln_b     = (const float*)d_in[21];
    const float* lm_w      = (const float*)d_in[22];
    float* out = (float*)d_out;
    float* ws  = (float*)d_ws;

    const long R = (long)BB * SS;           // 2048 rows
    float* te    = ws;                      // R*512 = 1048576
    float* cbuf  = te   + 1048576;          // R*320
    float* x     = cbuf + 655360;
    float* lnbuf = x    + 655360;
    float* qkv   = lnbuf + 655360;          // R*960
    float* ctx   = qkv  + 1966080;
    float* attn  = ctx  + 655360;
    float* mlp1  = attn + 655360;           // R*1024

    embed_ln_kernel<<<R, 64, 0, stream>>>(ids, embed_w, embed_nw, embed_nb, te);
    // c = te @ Wbot + dproj_b   (Wbot = dproj_w rows 320..831)
    gemm_kernel<<<dim3(PP / 64, R / 64), 256, 0, stream>>>(
        te, dproj_w + (long)PP * PP, dproj_b, cbuf, R, PP, EE, 0, 0, nullptr, nullptr);
    scan_kernel<<<1, 256, 0, stream>>>(dproj_w, cbuf, dproj_lnw, dproj_lnb, x);

    for (int l = 0; l < NL; ++l) {
        ln_kernel<<<R, 64, 0, stream>>>(x, ln1_w + l * PP, ln1_b + l * PP, lnbuf, PP);
        gemm_kernel<<<dim3(960 / 64, R / 64), 256, 0, stream>>>(
            lnbuf, qkv_w + (long)l * PP * 960, qkv_b + l * 960, qkv, R, 960, PP, 0, 0, nullptr, nullptr);
        rope_kernel<<<(BB * SS * NH + 255) / 256, 256, 0, stream>>>(qkv);
        attn_kernel<<<BB * NH * 16, 256, 0, stream>>>(qkv, ctx);
        gemm_kernel<<<dim3(PP / 64, R / 64), 256, 0, stream>>>(
            ctx, dense_w + (long)l * PP * PP, dense_b + l * PP, attn, R, PP, PP, 0, 0, nullptr, nullptr);
        ln_kernel<<<R, 64, 0, stream>>>(x, ln2_w + l * PP, ln2_b + l * PP, lnbuf, PP);
        gemm_kernel<<<dim3(II / 64, R / 64), 256, 0, stream>>>(
            lnbuf, fc1_w + (long)l * PP * II, fc1_b + l * II, mlp1, R, II, PP, 0, 1, nullptr, nullptr);
        // x = x + attn + fc2(mlp1)
        gemm_kernel<<<dim3(PP / 64, R / 64), 256, 0, stream>>>(
            mlp1, fc2_w + (long)l * II * PP, fc2_b + l * PP, x, R, PP, II, 0, 0, x, attn);
    }
    ln_kernel<<<R, 64, 0, stream>>>(x, fln_w, fln_b, lnbuf, PP);
    // logits = lnbuf @ lm_w^T   (lm_w is (V,P) row-major -> BT=1)
    gemm_kernel<<<dim3(VV / 64, R / 64), 256, 0, stream>>>(
        lnbuf, lm_w, nullptr, out, R, VV, PP, 1, 0, nullptr, nullptr);
}